// Round 1
// baseline (394.789 us; speedup 1.0000x reference)
//
#include <hip/hip_runtime.h>
#include <hip/hip_bf16.h>
#include <cstdint>
#include <cstddef>

#define B_ 8
#define N_ 4096
#define DIM_ 768
#define H_ 12
#define HD_ 64
#define M_ (B_*N_)        // 32768
#define SCALE_ 0.125f
#define NSPLIT 16

typedef __attribute__((ext_vector_type(8))) short s8v;
typedef __attribute__((ext_vector_type(4))) float f4v;

__device__ inline float bf2f(unsigned short u) {
    unsigned v = ((unsigned)u) << 16;
    return __builtin_bit_cast(float, v);
}
__device__ inline unsigned short f2bf(float f) {
    unsigned u = __builtin_bit_cast(unsigned, f);
    unsigned r = (u + 0x7FFFu + ((u >> 16) & 1u)) >> 16;
    return (unsigned short)r;
}

__device__ inline void gload16(const void* g, void* l) {
    __builtin_amdgcn_global_load_lds(
        (const __attribute__((address_space(1))) void*)g,
        (__attribute__((address_space(3))) void*)l, 16, 0, 0);
}

// f32 -> bf16 conversion, 4 elems/thread
__global__ void cvt_kernel(const float* __restrict__ src, unsigned short* __restrict__ dst, int n4) {
    int i = blockIdx.x * 256 + threadIdx.x;
    if (i >= n4) return;
    float4 v = ((const float4*)src)[i];
    ushort4 o;
    o.x = f2bf(v.x); o.y = f2bf(v.y); o.z = f2bf(v.z); o.w = f2bf(v.w);
    ((ushort4*)dst)[i] = o;
}

// C[M,Nc] = A[M,K] @ W[Nc,K]^T.  A,W bf16 row-major. EPI==0: store bf16.
// EPI==1: out f32 = C + bias[col] + bf2f(Qf[row*2304+col])
template<int EPI>
__global__ __launch_bounds__(256)
void gemm_bt(const unsigned short* __restrict__ A,
             const unsigned short* __restrict__ W,
             unsigned short* __restrict__ Cb,
             float* __restrict__ Cf,
             const float* __restrict__ bias,
             const unsigned short* __restrict__ Qf,
             int M, int Nc, int K, int ntiles_n)
{
    __shared__ __align__(16) unsigned short sA[128 * 64];
    __shared__ __align__(16) unsigned short sB[128 * 64];
    int tid = threadIdx.x;
    int l = tid & 63, w = tid >> 6;
    int wr = w >> 1, wc = w & 1;
    int bid = blockIdx.x;
    int tn = bid % ntiles_n, tm = bid / ntiles_n;
    int m0 = tm * 128, n0 = tn * 128;

    f4v acc[4][4] = {};

    int srow = tid >> 3;             // staging row within 32-row group
    int scol = (tid & 7) * 8;        // staging k-offset (elements)
    const unsigned short* Ab = A + (size_t)(m0 + srow) * K + scol;
    const unsigned short* Wb = W + (size_t)(n0 + srow) * K + scol;
    char* sAb = (char*)sA + w * 1024;
    char* sBb = (char*)sB + w * 1024;

    for (int kt = 0; kt < K; kt += 64) {
#pragma unroll
        for (int i = 0; i < 4; i++) {
            gload16(Ab + (size_t)(i * 32) * K + kt, sAb + i * 4096);
            gload16(Wb + (size_t)(i * 32) * K + kt, sBb + i * 4096);
        }
        __syncthreads();
        int lr = l & 15, lk = (l >> 4) * 8;
#pragma unroll
        for (int kk = 0; kk < 64; kk += 32) {
            s8v a[4], b[4];
#pragma unroll
            for (int m = 0; m < 4; m++)
                a[m] = *(const s8v*)&sA[(wr * 64 + m * 16 + lr) * 64 + kk + lk];
#pragma unroll
            for (int n = 0; n < 4; n++)
                b[n] = *(const s8v*)&sB[(wc * 64 + n * 16 + lr) * 64 + kk + lk];
#pragma unroll
            for (int m = 0; m < 4; m++)
#pragma unroll
                for (int n = 0; n < 4; n++)
                    acc[m][n] = __builtin_amdgcn_mfma_f32_16x16x32_bf16(a[m], b[n], acc[m][n], 0, 0, 0);
        }
        __syncthreads();
    }

    int lr = l & 15, lq = l >> 4;
#pragma unroll
    for (int m = 0; m < 4; m++) {
#pragma unroll
        for (int n = 0; n < 4; n++) {
            int col = n0 + wc * 64 + n * 16 + lr;
#pragma unroll
            for (int r = 0; r < 4; r++) {
                int row = m0 + wr * 64 + m * 16 + lq * 4 + r;
                float vacc = acc[m][n][r];
                if (EPI == 0) {
                    Cb[(size_t)row * Nc + col] = f2bf(vacc);
                } else {
                    float o = vacc + bias[col] + bf2f(Qf[(size_t)row * 2304 + col]);
                    Cf[(size_t)row * Nc + col] = o;
                }
            }
        }
    }
}

// out[b,h,n] = SCALE * dot(qkv[(b,n), col_off + h*64 .. +64], vec)
// per_bh: vec indexed by (b*H+h)*64, else h*64
__global__ void dots_kernel(const unsigned short* __restrict__ qkv, int col_off,
                            const float* __restrict__ vec, int per_bh,
                            float* __restrict__ out)
{
    int idx = blockIdx.x * 256 + threadIdx.x;   // B*H*N total
    int n = idx & (N_ - 1);
    int t12 = idx >> 12;
    int h = t12 % H_;
    int b = t12 / H_;
    const unsigned short* q = qkv + (size_t)(b * N_ + n) * 2304 + col_off + h * 64;
    const float* v = vec + (per_bh ? (b * H_ + h) * 64 : h * 64);
    float s = 0.f;
#pragma unroll
    for (int j = 0; j < 8; j++) {
        s8v q8 = *(const s8v*)&q[j * 8];
#pragma unroll
        for (int e = 0; e < 8; e++)
            s += bf2f((unsigned short)q8[e]) * v[j * 8 + e];
    }
    out[idx] = s * SCALE_;
}

// per (b,h): max and exp-sum over N_ values
__global__ void smstats_kernel(const float* __restrict__ alpha, float* __restrict__ ms)
{
    int bh = blockIdx.x;
    const float* a = alpha + (size_t)bh * N_;
    int t = threadIdx.x;
    float v[16];
#pragma unroll
    for (int i = 0; i < 16; i++) v[i] = a[t + i * 256];
    float m = v[0];
#pragma unroll
    for (int i = 1; i < 16; i++) m = fmaxf(m, v[i]);
#pragma unroll
    for (int o = 32; o >= 1; o >>= 1) m = fmaxf(m, __shfl_xor(m, o));
    __shared__ float red[4];
    if ((t & 63) == 0) red[t >> 6] = m;
    __syncthreads();
    m = fmaxf(fmaxf(red[0], red[1]), fmaxf(red[2], red[3]));
    float s = 0.f;
#pragma unroll
    for (int i = 0; i < 16; i++) s += __expf(v[i] - m);
#pragma unroll
    for (int o = 32; o >= 1; o >>= 1) s += __shfl_xor(s, o);
    __shared__ float red2[4];
    if ((t & 63) == 0) red2[t >> 6] = s;
    __syncthreads();
    if (t == 0) {
        ms[bh * 2] = m;
        ms[bh * 2 + 1] = red2[0] + red2[1] + red2[2] + red2[3];
    }
}

// partial weighted sums: part[bh, split, c] = sum_{n in split} w_n * src[n, c]
__global__ void wsum_partial_kernel(const unsigned short* __restrict__ qkv, int col_off,
                                    const float* __restrict__ alpha, const float* __restrict__ ms,
                                    float* __restrict__ part)
{
    int bh = blockIdx.x / NSPLIT, sp = blockIdx.x % NSPLIT;
    int b = bh / H_, h = bh % H_;
    int t = threadIdx.x;
    int n0 = sp * (N_ / NSPLIT);   // 256 rows per split
    __shared__ float wv[256];
    float m = ms[bh * 2], s = ms[bh * 2 + 1];
    wv[t] = __expf(alpha[(size_t)bh * N_ + n0 + t] - m) / s;
    __syncthreads();
    int c = t & 63, g = t >> 6;
    const unsigned short* src = qkv + (size_t)(b * N_ + n0) * 2304 + col_off + h * 64 + c;
    float acc = 0.f;
    for (int i = g; i < 256; i += 4)
        acc += wv[i] * bf2f(src[(size_t)i * 2304]);
    __shared__ float red[256];
    red[t] = acc;
    __syncthreads();
    if (t < 64)
        part[((size_t)bh * NSPLIT + sp) * 64 + t] = red[t] + red[t + 64] + red[t + 128] + red[t + 192];
}

// reduce partials -> gout[bh,c]; optionally bvec = gout * wk[h,c]
__global__ void wsum_reduce_kernel(const float* __restrict__ part, float* __restrict__ gout,
                                   const float* __restrict__ wk, float* __restrict__ bvec)
{
    int bh = blockIdx.x;
    int t = threadIdx.x;   // 64 threads
    int h = bh % H_;
    float s = 0.f;
#pragma unroll
    for (int i = 0; i < NSPLIT; i++) s += part[((size_t)bh * NSPLIT + i) * 64 + t];
    gout[bh * 64 + t] = s;
    if (wk) bvec[bh * 64 + t] = s * wk[h * 64 + t];
}

// ub[row, col] = bf16( gk[b, h, c] * v[row, col] ),  v at qkv col 1536+col
__global__ void scale_v_kernel(const unsigned short* __restrict__ qkv, const float* __restrict__ gk,
                               unsigned short* __restrict__ ub)
{
    size_t i8 = ((size_t)blockIdx.x * 256 + threadIdx.x) * 8;
    int col = (int)(i8 % 768);
    size_t row = i8 / 768;
    int b = (int)(row >> 12);
    int h = col >> 6, c = col & 63;
    s8v v8 = *(const s8v*)&qkv[row * 2304 + 1536 + col];
    const float* g = gk + ((size_t)b * H_ + h) * 64 + c;
    s8v o;
#pragma unroll
    for (int e = 0; e < 8; e++)
        o[e] = (short)f2bf(bf2f((unsigned short)v8[e]) * g[e]);
    *(s8v*)&ub[i8] = o;
}

extern "C" void kernel_launch(void* const* d_in, const int* in_sizes, int n_in,
                              void* d_out, int out_size, void* d_ws, size_t ws_size,
                              hipStream_t stream)
{
    const float* x    = (const float*)d_in[0];
    const float* Wqkv = (const float*)d_in[1];
    const float* Wp   = (const float*)d_in[2];
    const float* bp   = (const float*)d_in[3];
    const float* w_q  = (const float*)d_in[4];
    const float* w_k  = (const float*)d_in[5];
    float* out = (float*)d_out;

    constexpr size_t NXB   = (size_t)M_ * DIM_;        // 25165824
    constexpr size_t NWQKV = (size_t)3 * DIM_ * DIM_;  // 1769472
    constexpr size_t NWP   = (size_t)DIM_ * DIM_;      // 589824
    constexpr size_t NQKV  = (size_t)M_ * 3 * DIM_;    // 75497472
    constexpr size_t NU    = (size_t)M_ * DIM_;

    char* p = (char*)d_ws;
    unsigned short* xb    = (unsigned short*)p; p += NXB * 2;
    unsigned short* wqkvb = (unsigned short*)p; p += NWQKV * 2;
    unsigned short* wpb   = (unsigned short*)p; p += NWP * 2;
    unsigned short* qkvb  = (unsigned short*)p; p += NQKV * 2;
    unsigned short* ub    = (unsigned short*)p; p += NU * 2;
    float* alpha = (float*)p; p += (size_t)B_ * H_ * N_ * 4;
    float* msA   = (float*)p; p += (size_t)B_ * H_ * 2 * 4;
    float* msB   = (float*)p; p += (size_t)B_ * H_ * 2 * 4;
    float* part  = (float*)p; p += (size_t)B_ * H_ * NSPLIT * 64 * 4;
    float* gq    = (float*)p; p += (size_t)B_ * H_ * 64 * 4;
    float* bvec  = (float*)p; p += (size_t)B_ * H_ * 64 * 4;
    float* gk    = (float*)p; p += (size_t)B_ * H_ * 64 * 4;

    // 1) convert inputs to bf16
    cvt_kernel<<<(int)(NXB / 4 + 255) / 256, 256, 0, stream>>>(x, xb, (int)(NXB / 4));
    cvt_kernel<<<(int)(NWQKV / 4 + 255) / 256, 256, 0, stream>>>(Wqkv, wqkvb, (int)(NWQKV / 4));
    cvt_kernel<<<(int)(NWP / 4 + 255) / 256, 256, 0, stream>>>(Wp, wpb, (int)(NWP / 4));

    // 2) qkv = x @ Wqkv^T   [M, 2304] bf16
    gemm_bt<0><<<256 * 18, 256, 0, stream>>>(xb, wqkvb, qkvb, nullptr, nullptr, nullptr,
                                             M_, 3 * DIM_, DIM_, 18);

    // 3) alpha path (q)
    dots_kernel<<<(B_ * H_ * N_) / 256, 256, 0, stream>>>(qkvb, 0, w_q, 0, alpha);
    smstats_kernel<<<B_ * H_, 256, 0, stream>>>(alpha, msA);
    wsum_partial_kernel<<<B_ * H_ * NSPLIT, 256, 0, stream>>>(qkvb, 0, alpha, msA, part);
    wsum_reduce_kernel<<<B_ * H_, 64, 0, stream>>>(part, gq, w_k, bvec);

    // 4) beta path (k)
    dots_kernel<<<(B_ * H_ * N_) / 256, 256, 0, stream>>>(qkvb, DIM_, bvec, 1, alpha);
    smstats_kernel<<<B_ * H_, 256, 0, stream>>>(alpha, msB);
    wsum_partial_kernel<<<B_ * H_ * NSPLIT, 256, 0, stream>>>(qkvb, DIM_, alpha, msB, part);
    wsum_reduce_kernel<<<B_ * H_, 64, 0, stream>>>(part, gk, nullptr, nullptr);

    // 5) u = global_k * v  (bf16)
    scale_v_kernel<<<(int)(NU / 8 / 256), 256, 0, stream>>>(qkvb, gk, ub);

    // 6) out = u @ Wp^T + bp + q_flat
    gemm_bt<1><<<256 * 6, 256, 0, stream>>>(ub, wpb, nullptr, out, bp, qkvb,
                                            M_, DIM_, DIM_, 6);
}

// Round 2
// 304.511 us; speedup vs baseline: 1.2965x; 1.2965x over previous
//
#include <hip/hip_runtime.h>
#include <hip/hip_bf16.h>
#include <cstdint>
#include <cstddef>

#define B_ 8
#define N_ 4096
#define DIM_ 768
#define H_ 12
#define M_ (B_*N_)        // 32768
#define SCALE_ 0.125f
#define NSPLIT 16
#define KDIM 768
#define NKT 12            // K tiles of 64
#define NITER 6           // NKT/2

typedef __attribute__((ext_vector_type(8))) short s8v;
typedef __attribute__((ext_vector_type(4))) float f4v;

__device__ inline float bf2f(unsigned short u) {
    unsigned v = ((unsigned)u) << 16;
    return __builtin_bit_cast(float, v);
}
__device__ inline unsigned short f2bf(float f) {
    unsigned u = __builtin_bit_cast(unsigned, f);
    return (unsigned short)((u + 0x7FFFu + ((u >> 16) & 1u)) >> 16);
}
__device__ inline void gload16(const void* g, void* l) {
    __builtin_amdgcn_global_load_lds(
        (const __attribute__((address_space(1))) void*)g,
        (__attribute__((address_space(3))) void*)l, 16, 0, 0);
}

// ---------------- 256x256 8-phase bf16 GEMM: C = A[M,768] @ B[Nc,768]^T ----------------
// EPI==0: store bf16 to Cb.  EPI==1: Cf = acc + bias[col] + bf2f(Qf[row*2304+col]),
//         B is per-batch (batch = row/4096): Bp = Bmat + batch*DIM_*DIM_.
template<int EPI>
__global__ __launch_bounds__(512, 2)
void gemm8(const unsigned short* __restrict__ A, int ldaE,
           const unsigned short* __restrict__ Bmat,
           unsigned short* __restrict__ Cb, float* __restrict__ Cf,
           const float* __restrict__ bias, const unsigned short* __restrict__ Qf,
           int Nc, int ntn)
{
    __shared__ __align__(16) char smem[131072];   // 2 bufs x 4 regions x 16KB
    const int tid = threadIdx.x;
    const int l = tid & 63, w = tid >> 6;
    const int lr = l & 15, g = l >> 4;
    const int wm = w >> 2, wn = w & 3;

    // XCD-aware bijective swizzle (grid % 8 == 0 for both uses)
    const int nwg = gridDim.x, cpx = nwg >> 3;
    const int bid = blockIdx.x;
    const int lg = (bid & 7) * cpx + (bid >> 3);
    const int tm = lg / ntn, tn = lg % ntn;
    const int m0 = tm * 256, n0 = tn * 256;

    const long ldaB = (long)ldaE * 2;
    const long ldbB = (long)KDIM * 2;

    const unsigned short* Bp = Bmat;
    if (EPI == 1) Bp = Bmat + (size_t)(m0 >> 12) * (DIM_ * DIM_);

    // per-thread staging source offsets (pre-swizzled global source, linear LDS dest)
    const int srA = w * 8 + (l >> 3);          // staging row within 8KB chunk
    const int kbs = (l & 7) * 16;              // linear kbyte within row
    const int kbx = kbs ^ ((srA & 7) << 4);    // swizzled source kbyte
    long offA[2], offB[2];
    offA[0] = (long)(srA) * ldaB + kbx;
    offA[1] = (long)(128 + srA) * ldaB + kbx;
    offB[0] = (long)(((srA >> 5)) * 64 + (srA & 31)) * ldbB + kbx;
    offB[1] = (long)((2 + (srA >> 5)) * 64 + (srA & 31)) * ldbB + kbx;

    const char* Abase = (const char*)(A + (size_t)m0 * ldaE);
    const char* Bbase = (const char*)(Bp + (size_t)n0 * KDIM);

    // fragment read offsets (swizzled)
    const int aoff = (wm * 64 + lr) * 128;
    const int boff = (wn * 32 + lr) * 128;
    const int kx0 = (g * 16) ^ ((lr & 7) << 4);
    const int kx1 = (64 + g * 16) ^ ((lr & 7) << 4);

    f4v acc[8][4] = {};
    s8v af[4][2];
    s8v bfr[2][2][2];

#define STG_A(buf_, qm_, kt_) { \
    const char* s0_ = Abase + (long)(kt_) * 2 + (long)(qm_) * 64 * ldaB; \
    char* d0_ = smem + ((buf_) * 4 + (qm_)) * 16384 + w * 1024; \
    gload16(s0_ + offA[0], d0_); \
    gload16(s0_ + offA[1], d0_ + 8192); }

#define STG_B(buf_, qn_, kt_) { \
    const char* s0_ = Bbase + (long)(kt_) * 2 + (long)(qn_) * 32 * ldbB; \
    char* d0_ = smem + ((buf_) * 4 + 2 + (qn_)) * 16384 + w * 1024; \
    gload16(s0_ + offB[0], d0_); \
    gload16(s0_ + offB[1], d0_ + 8192); }

#define DS_A(buf_, qm_) { \
    const char* ba_ = smem + ((buf_) * 4 + (qm_)) * 16384 + aoff; \
    af[0][0] = *(const s8v*)(ba_ +    0 + kx0); af[0][1] = *(const s8v*)(ba_ +    0 + kx1); \
    af[1][0] = *(const s8v*)(ba_ + 2048 + kx0); af[1][1] = *(const s8v*)(ba_ + 2048 + kx1); \
    af[2][0] = *(const s8v*)(ba_ + 4096 + kx0); af[2][1] = *(const s8v*)(ba_ + 4096 + kx1); \
    af[3][0] = *(const s8v*)(ba_ + 6144 + kx0); af[3][1] = *(const s8v*)(ba_ + 6144 + kx1); }

#define DS_B(buf_, qn_) { \
    const char* bb_ = smem + ((buf_) * 4 + 2 + (qn_)) * 16384 + boff; \
    bfr[qn_][0][0] = *(const s8v*)(bb_ +    0 + kx0); bfr[qn_][0][1] = *(const s8v*)(bb_ +    0 + kx1); \
    bfr[qn_][1][0] = *(const s8v*)(bb_ + 2048 + kx0); bfr[qn_][1][1] = *(const s8v*)(bb_ + 2048 + kx1); }

#define MM(fmg_, fng_, qn_, kk_) \
    acc[fmg_][fng_] = __builtin_amdgcn_mfma_f32_16x16x32_bf16(af[(fmg_)&3][kk_], bfr[qn_][(fng_)&1][kk_], acc[fmg_][fng_], 0, 0, 0);

#define MFMA8(qm_, qn_, kk_) \
    MM((qm_)*4+0, (qn_)*2+0, qn_, kk_) MM((qm_)*4+0, (qn_)*2+1, qn_, kk_) \
    MM((qm_)*4+1, (qn_)*2+0, qn_, kk_) MM((qm_)*4+1, (qn_)*2+1, qn_, kk_) \
    MM((qm_)*4+2, (qn_)*2+0, qn_, kk_) MM((qm_)*4+2, (qn_)*2+1, qn_, kk_) \
    MM((qm_)*4+3, (qn_)*2+0, qn_, kk_) MM((qm_)*4+3, (qn_)*2+1, qn_, kk_)

#define MFMA16(qm_, qn_) { MFMA8(qm_, qn_, 0) MFMA8(qm_, qn_, 1) }

#define BARX() __builtin_amdgcn_s_barrier()
#define PRIO1() __builtin_amdgcn_s_setprio(1)
#define PRIO0() __builtin_amdgcn_s_setprio(0)
#define VM4() asm volatile("s_waitcnt vmcnt(4)" ::: "memory")
#define VM0() asm volatile("s_waitcnt vmcnt(0)" ::: "memory")

    // prologue: T0 all 4 regions, then T1.Aq0, T1.Bq0  (12 loads/wave)
    STG_A(0, 0, 0); STG_B(0, 0, 0); STG_A(0, 1, 0); STG_B(0, 1, 0);
    STG_A(1, 0, 64); STG_B(1, 0, 64);
    VM4(); BARX();

    for (int i = 0; i < NITER; ++i) {
        const int t1k = (2 * i + 1) * 64, t2k = (2 * i + 2) * 64, t3k = (2 * i + 3) * 64;
        const bool h2 = (2 * i + 2) < NKT, h3 = (2 * i + 3) < NKT;
        const bool last = (i == NITER - 1);
        // ph1: quadrant (0,0) on buf0
        DS_A(0, 0); DS_B(0, 0); STG_B(1, 1, t1k);
        BARX(); PRIO1(); MFMA16(0, 0); PRIO0(); BARX();
        // ph2: (0,1)
        DS_B(0, 1); STG_A(1, 1, t1k);
        BARX(); PRIO1(); MFMA16(0, 1); PRIO0(); BARX();
        // ph3: (1,0)
        DS_A(0, 1); if (h2) STG_A(0, 0, t2k);
        BARX(); PRIO1(); MFMA16(1, 0); PRIO0(); BARX();
        // ph4: (1,1)  + tile-boundary counted wait
        if (h2) STG_B(0, 0, t2k);
        BARX(); PRIO1(); MFMA16(1, 1); PRIO0();
        if (last) { VM0(); } else { VM4(); }
        BARX();
        // ph5: (0,0) on buf1
        DS_A(1, 0); DS_B(1, 0); if (h2) STG_A(0, 1, t2k);
        BARX(); PRIO1(); MFMA16(0, 0); PRIO0(); BARX();
        // ph6: (0,1)
        DS_B(1, 1); if (h2) STG_B(0, 1, t2k);
        BARX(); PRIO1(); MFMA16(0, 1); PRIO0(); BARX();
        // ph7: (1,0)
        DS_A(1, 1); if (h3) STG_A(1, 0, t3k);
        BARX(); PRIO1(); MFMA16(1, 0); PRIO0(); BARX();
        // ph8: (1,1) + boundary wait
        if (h3) STG_B(1, 0, t3k);
        BARX(); PRIO1(); MFMA16(1, 1); PRIO0();
        if (last) { VM0(); } else { VM4(); }
        BARX();
    }

    // epilogue: direct stores (C/D layout: row = g*4+r, col = lr)
#pragma unroll
    for (int fmg = 0; fmg < 8; ++fmg) {
#pragma unroll
        for (int fng = 0; fng < 4; ++fng) {
            const int col = n0 + wn * 64 + fng * 16 + lr;
#pragma unroll
            for (int r = 0; r < 4; ++r) {
                const int row = m0 + wm * 128 + fmg * 16 + g * 4 + r;
                const float v = acc[fmg][fng][r];
                if (EPI == 0) {
                    Cb[(size_t)row * Nc + col] = f2bf(v);
                } else {
                    Cf[(size_t)row * Nc + col] = v + bias[col] + bf2f(Qf[(size_t)row * 2304 + col]);
                }
            }
        }
    }
#undef STG_A
#undef STG_B
#undef DS_A
#undef DS_B
#undef MM
#undef MFMA8
#undef MFMA16
}

// ---------------- small kernels ----------------

__global__ void cvt_kernel(const float* __restrict__ src, unsigned short* __restrict__ dst, int n4) {
    int i = blockIdx.x * 256 + threadIdx.x;
    if (i >= n4) return;
    float4 v = ((const float4*)src)[i];
    ushort4 o;
    o.x = f2bf(v.x); o.y = f2bf(v.y); o.z = f2bf(v.z); o.w = f2bf(v.w);
    ((ushort4*)dst)[i] = o;
}

// W2[b][j][c] = bf16(Wp[j][c] * gk[(b*H + c/64)*64 + c%64])
__global__ void fold_wp(const float* __restrict__ Wp, const float* __restrict__ gk,
                        unsigned short* __restrict__ W2) {
    int idx = blockIdx.x * 256 + threadIdx.x;       // 1179648 total (x4 elems)
    int e4 = idx * 4;
    int b = (int)((unsigned)e4 / (unsigned)(DIM_ * DIM_));
    int rem = e4 - b * (DIM_ * DIM_);
    int c = rem % DIM_;
    float4 wv = *(const float4*)&Wp[rem];
    const float* gp = &gk[(b * H_ + (c >> 6)) * 64 + (c & 63)];
    ushort4 o;
    o.x = f2bf(wv.x * gp[0]); o.y = f2bf(wv.y * gp[1]);
    o.z = f2bf(wv.z * gp[2]); o.w = f2bf(wv.w * gp[3]);
    *(ushort4*)&W2[e4] = o;
}

__global__ void dots_kernel(const unsigned short* __restrict__ qkv, int col_off,
                            const float* __restrict__ vec, int per_bh,
                            float* __restrict__ out)
{
    int idx = blockIdx.x * 256 + threadIdx.x;
    int n = idx & (N_ - 1);
    int t12 = idx >> 12;
    int h = t12 % H_;
    int b = t12 / H_;
    const unsigned short* q = qkv + (size_t)(b * N_ + n) * 2304 + col_off + h * 64;
    const float* v = vec + (per_bh ? (b * H_ + h) * 64 : h * 64);
    float s = 0.f;
#pragma unroll
    for (int j = 0; j < 8; j++) {
        s8v q8 = *(const s8v*)&q[j * 8];
#pragma unroll
        for (int e = 0; e < 8; e++)
            s += bf2f((unsigned short)q8[e]) * v[j * 8 + e];
    }
    out[idx] = s * SCALE_;
}

__global__ void smstats_kernel(const float* __restrict__ alpha, float* __restrict__ ms)
{
    int bh = blockIdx.x;
    const float* a = alpha + (size_t)bh * N_;
    int t = threadIdx.x;
    float v[16];
#pragma unroll
    for (int i = 0; i < 16; i++) v[i] = a[t + i * 256];
    float m = v[0];
#pragma unroll
    for (int i = 1; i < 16; i++) m = fmaxf(m, v[i]);
#pragma unroll
    for (int o = 32; o >= 1; o >>= 1) m = fmaxf(m, __shfl_xor(m, o));
    __shared__ float red[4];
    if ((t & 63) == 0) red[t >> 6] = m;
    __syncthreads();
    m = fmaxf(fmaxf(red[0], red[1]), fmaxf(red[2], red[3]));
    float s = 0.f;
#pragma unroll
    for (int i = 0; i < 16; i++) s += __expf(v[i] - m);
#pragma unroll
    for (int o = 32; o >= 1; o >>= 1) s += __shfl_xor(s, o);
    __shared__ float red2[4];
    if ((t & 63) == 0) red2[t >> 6] = s;
    __syncthreads();
    if (t == 0) {
        ms[bh * 2] = m;
        ms[bh * 2 + 1] = red2[0] + red2[1] + red2[2] + red2[3];
    }
}

__global__ void wsum_partial_kernel(const unsigned short* __restrict__ qkv, int col_off,
                                    const float* __restrict__ alpha, const float* __restrict__ ms,
                                    float* __restrict__ part)
{
    int bh = blockIdx.x / NSPLIT, sp = blockIdx.x % NSPLIT;
    int b = bh / H_, h = bh % H_;
    int t = threadIdx.x;
    int n0 = sp * (N_ / NSPLIT);
    __shared__ float wv[256];
    float m = ms[bh * 2], s = ms[bh * 2 + 1];
    wv[t] = __expf(alpha[(size_t)bh * N_ + n0 + t] - m) / s;
    __syncthreads();
    int c = t & 63, gg = t >> 6;
    const unsigned short* src = qkv + (size_t)(b * N_ + n0) * 2304 + col_off + h * 64 + c;
    float acc = 0.f;
    for (int i = gg; i < 256; i += 4)
        acc += wv[i] * bf2f(src[(size_t)i * 2304]);
    __shared__ float red[256];
    red[t] = acc;
    __syncthreads();
    if (t < 64)
        part[((size_t)bh * NSPLIT + sp) * 64 + t] = red[t] + red[t + 64] + red[t + 128] + red[t + 192];
}

__global__ void wsum_reduce_kernel(const float* __restrict__ part, float* __restrict__ gout,
                                   const float* __restrict__ wk, float* __restrict__ bvec)
{
    int bh = blockIdx.x;
    int t = threadIdx.x;
    int h = bh % H_;
    float s = 0.f;
#pragma unroll
    for (int i = 0; i < NSPLIT; i++) s += part[((size_t)bh * NSPLIT + i) * 64 + t];
    gout[bh * 64 + t] = s;
    if (wk) bvec[bh * 64 + t] = s * wk[h * 64 + t];
}

extern "C" void kernel_launch(void* const* d_in, const int* in_sizes, int n_in,
                              void* d_out, int out_size, void* d_ws, size_t ws_size,
                              hipStream_t stream)
{
    const float* x    = (const float*)d_in[0];
    const float* Wqkv = (const float*)d_in[1];
    const float* Wp   = (const float*)d_in[2];
    const float* bp   = (const float*)d_in[3];
    const float* w_q  = (const float*)d_in[4];
    const float* w_k  = (const float*)d_in[5];
    float* out = (float*)d_out;

    constexpr size_t NXB   = (size_t)M_ * DIM_;
    constexpr size_t NWQKV = (size_t)3 * DIM_ * DIM_;
    constexpr size_t NQKV  = (size_t)M_ * 3 * DIM_;
    constexpr size_t NW2   = (size_t)B_ * DIM_ * DIM_;

    char* p = (char*)d_ws;
    unsigned short* xb    = (unsigned short*)p; p += NXB * 2;
    unsigned short* wqkvb = (unsigned short*)p; p += NWQKV * 2;
    unsigned short* qkvb  = (unsigned short*)p; p += NQKV * 2;
    unsigned short* w2b   = (unsigned short*)p; p += NW2 * 2;
    float* alpha = (float*)p; p += (size_t)B_ * H_ * N_ * 4;
    float* msA   = (float*)p; p += (size_t)B_ * H_ * 2 * 4;
    float* msB   = (float*)p; p += (size_t)B_ * H_ * 2 * 4;
    float* part  = (float*)p; p += (size_t)B_ * H_ * NSPLIT * 64 * 4;
    float* gq    = (float*)p; p += (size_t)B_ * H_ * 64 * 4;
    float* bvec  = (float*)p; p += (size_t)B_ * H_ * 64 * 4;
    float* gk    = (float*)p; p += (size_t)B_ * H_ * 64 * 4;

    // 1) convert x, Wqkv to bf16
    cvt_kernel<<<(int)(NXB / 4 + 255) / 256, 256, 0, stream>>>(x, xb, (int)(NXB / 4));
    cvt_kernel<<<(int)(NWQKV / 4 + 255) / 256, 256, 0, stream>>>(Wqkv, wqkvb, (int)(NWQKV / 4));

    // 2) qkv = x @ Wqkv^T  [M, 2304] bf16   (128 x 9 tiles of 256^2)
    gemm8<0><<<128 * 9, 512, 0, stream>>>(xb, DIM_, wqkvb, qkvb, nullptr, nullptr, nullptr,
                                          3 * DIM_, 9);

    // 3) alpha path (q)
    dots_kernel<<<(B_ * H_ * N_) / 256, 256, 0, stream>>>(qkvb, 0, w_q, 0, alpha);
    smstats_kernel<<<B_ * H_, 256, 0, stream>>>(alpha, msA);
    wsum_partial_kernel<<<B_ * H_ * NSPLIT, 256, 0, stream>>>(qkvb, 0, alpha, msA, part);
    wsum_reduce_kernel<<<B_ * H_, 64, 0, stream>>>(part, gq, w_k, bvec);

    // 4) beta path (k)
    dots_kernel<<<(B_ * H_ * N_) / 256, 256, 0, stream>>>(qkvb, DIM_, bvec, 1, alpha);
    smstats_kernel<<<B_ * H_, 256, 0, stream>>>(alpha, msB);
    wsum_partial_kernel<<<B_ * H_ * NSPLIT, 256, 0, stream>>>(qkvb, DIM_, alpha, msB, part);
    wsum_reduce_kernel<<<B_ * H_, 64, 0, stream>>>(part, gk, nullptr, nullptr);

    // 5) fold gk into Wp: W2[b] = Wp * gk_b   (bf16)
    fold_wp<<<(int)(NW2 / 4 / 256), 256, 0, stream>>>(Wp, gk, w2b);

    // 6) out = v @ W2_b^T + bp + q_flat   (128 x 3 tiles of 256^2)
    gemm8<1><<<128 * 3, 512, 0, stream>>>(qkvb + 1536, 2304, w2b, nullptr, out, bp, qkvb,
                                          DIM_, 3);
}

// Round 3
// 252.091 us; speedup vs baseline: 1.5661x; 1.2079x over previous
//
#include <hip/hip_runtime.h>
#include <hip/hip_bf16.h>
#include <cstdint>
#include <cstddef>

#define B_ 8
#define N_ 4096
#define DIM_ 768
#define H_ 12
#define M_ (B_*N_)        // 32768
#define SCALE_ 0.125f
#define NS2 16            // row-splits per (b,h) for fused path
#define KDIM 768
#define NKT 12            // K tiles of 64
#define NITER 6           // NKT/2

typedef __attribute__((ext_vector_type(8))) short s8v;
typedef __attribute__((ext_vector_type(4))) float f4v;

__device__ inline float bf2f(unsigned short u) {
    unsigned v = ((unsigned)u) << 16;
    return __builtin_bit_cast(float, v);
}
__device__ inline unsigned short f2bf(float f) {
    unsigned u = __builtin_bit_cast(unsigned, f);
    return (unsigned short)((u + 0x7FFFu + ((u >> 16) & 1u)) >> 16);
}
__device__ inline void gload16(const void* g, void* l) {
    __builtin_amdgcn_global_load_lds(
        (const __attribute__((address_space(1))) void*)g,
        (__attribute__((address_space(3))) void*)l, 16, 0, 0);
}

// ---------------- 256x256 8-phase bf16 GEMM: C = A[M,768] @ B[Nc,768]^T ----------------
// EPI==0: store bf16 to Cb.  EPI==1: Cf = acc + bias[col] + bf2f(Qf[row*2304+col]),
//         B is per-batch (batch = row/4096): Bp = Bmat + batch*DIM_*DIM_.
template<int EPI>
__global__ __launch_bounds__(512, 2)
void gemm8(const unsigned short* __restrict__ A, int ldaE,
           const unsigned short* __restrict__ Bmat,
           unsigned short* __restrict__ Cb, float* __restrict__ Cf,
           const float* __restrict__ bias, const unsigned short* __restrict__ Qf,
           int Nc, int ntn)
{
    __shared__ __align__(16) char smem[131072];   // 2 bufs x 4 regions x 16KB
    const int tid = threadIdx.x;
    const int l = tid & 63, w = tid >> 6;
    const int lr = l & 15, g = l >> 4;
    const int wm = w >> 2, wn = w & 3;

    const int nwg = gridDim.x, cpx = nwg >> 3;
    const int bid = blockIdx.x;
    const int lg = (bid & 7) * cpx + (bid >> 3);
    const int tm = lg / ntn, tn = lg % ntn;
    const int m0 = tm * 256, n0 = tn * 256;

    const long ldaB = (long)ldaE * 2;
    const long ldbB = (long)KDIM * 2;

    const unsigned short* Bp = Bmat;
    if (EPI == 1) Bp = Bmat + (size_t)(m0 >> 12) * (DIM_ * DIM_);

    const int srA = w * 8 + (l >> 3);
    const int kbs = (l & 7) * 16;
    const int kbx = kbs ^ ((srA & 7) << 4);
    long offA[2], offB[2];
    offA[0] = (long)(srA) * ldaB + kbx;
    offA[1] = (long)(128 + srA) * ldaB + kbx;
    offB[0] = (long)(((srA >> 5)) * 64 + (srA & 31)) * ldbB + kbx;
    offB[1] = (long)((2 + (srA >> 5)) * 64 + (srA & 31)) * ldbB + kbx;

    const char* Abase = (const char*)(A + (size_t)m0 * ldaE);
    const char* Bbase = (const char*)(Bp + (size_t)n0 * KDIM);

    const int aoff = (wm * 64 + lr) * 128;
    const int boff = (wn * 32 + lr) * 128;
    const int kx0 = (g * 16) ^ ((lr & 7) << 4);
    const int kx1 = (64 + g * 16) ^ ((lr & 7) << 4);

    f4v acc[8][4] = {};
    s8v af[4][2];
    s8v bfr[2][2][2];

#define STG_A(buf_, qm_, kt_) { \
    const char* s0_ = Abase + (long)(kt_) * 2 + (long)(qm_) * 64 * ldaB; \
    char* d0_ = smem + ((buf_) * 4 + (qm_)) * 16384 + w * 1024; \
    gload16(s0_ + offA[0], d0_); \
    gload16(s0_ + offA[1], d0_ + 8192); }

#define STG_B(buf_, qn_, kt_) { \
    const char* s0_ = Bbase + (long)(kt_) * 2 + (long)(qn_) * 32 * ldbB; \
    char* d0_ = smem + ((buf_) * 4 + 2 + (qn_)) * 16384 + w * 1024; \
    gload16(s0_ + offB[0], d0_); \
    gload16(s0_ + offB[1], d0_ + 8192); }

#define DS_A(buf_, qm_) { \
    const char* ba_ = smem + ((buf_) * 4 + (qm_)) * 16384 + aoff; \
    af[0][0] = *(const s8v*)(ba_ +    0 + kx0); af[0][1] = *(const s8v*)(ba_ +    0 + kx1); \
    af[1][0] = *(const s8v*)(ba_ + 2048 + kx0); af[1][1] = *(const s8v*)(ba_ + 2048 + kx1); \
    af[2][0] = *(const s8v*)(ba_ + 4096 + kx0); af[2][1] = *(const s8v*)(ba_ + 4096 + kx1); \
    af[3][0] = *(const s8v*)(ba_ + 6144 + kx0); af[3][1] = *(const s8v*)(ba_ + 6144 + kx1); }

#define DS_B(buf_, qn_) { \
    const char* bb_ = smem + ((buf_) * 4 + 2 + (qn_)) * 16384 + boff; \
    bfr[qn_][0][0] = *(const s8v*)(bb_ +    0 + kx0); bfr[qn_][0][1] = *(const s8v*)(bb_ +    0 + kx1); \
    bfr[qn_][1][0] = *(const s8v*)(bb_ + 2048 + kx0); bfr[qn_][1][1] = *(const s8v*)(bb_ + 2048 + kx1); }

#define MM(fmg_, fng_, qn_, kk_) \
    acc[fmg_][fng_] = __builtin_amdgcn_mfma_f32_16x16x32_bf16(af[(fmg_)&3][kk_], bfr[qn_][(fng_)&1][kk_], acc[fmg_][fng_], 0, 0, 0);

#define MFMA8(qm_, qn_, kk_) \
    MM((qm_)*4+0, (qn_)*2+0, qn_, kk_) MM((qm_)*4+0, (qn_)*2+1, qn_, kk_) \
    MM((qm_)*4+1, (qn_)*2+0, qn_, kk_) MM((qm_)*4+1, (qn_)*2+1, qn_, kk_) \
    MM((qm_)*4+2, (qn_)*2+0, qn_, kk_) MM((qm_)*4+2, (qn_)*2+1, qn_, kk_) \
    MM((qm_)*4+3, (qn_)*2+0, qn_, kk_) MM((qm_)*4+3, (qn_)*2+1, qn_, kk_)

#define MFMA16(qm_, qn_) { MFMA8(qm_, qn_, 0) MFMA8(qm_, qn_, 1) }

#define BARX() __builtin_amdgcn_s_barrier()
#define PRIO1() __builtin_amdgcn_s_setprio(1)
#define PRIO0() __builtin_amdgcn_s_setprio(0)
#define VM4() asm volatile("s_waitcnt vmcnt(4)" ::: "memory")
#define VM0() asm volatile("s_waitcnt vmcnt(0)" ::: "memory")

    STG_A(0, 0, 0); STG_B(0, 0, 0); STG_A(0, 1, 0); STG_B(0, 1, 0);
    STG_A(1, 0, 64); STG_B(1, 0, 64);
    VM4(); BARX();

    for (int i = 0; i < NITER; ++i) {
        const int t1k = (2 * i + 1) * 64, t2k = (2 * i + 2) * 64, t3k = (2 * i + 3) * 64;
        const bool h2 = (2 * i + 2) < NKT, h3 = (2 * i + 3) < NKT;
        const bool last = (i == NITER - 1);
        DS_A(0, 0); DS_B(0, 0); STG_B(1, 1, t1k);
        BARX(); PRIO1(); MFMA16(0, 0); PRIO0(); BARX();
        DS_B(0, 1); STG_A(1, 1, t1k);
        BARX(); PRIO1(); MFMA16(0, 1); PRIO0(); BARX();
        DS_A(0, 1); if (h2) STG_A(0, 0, t2k);
        BARX(); PRIO1(); MFMA16(1, 0); PRIO0(); BARX();
        if (h2) STG_B(0, 0, t2k);
        BARX(); PRIO1(); MFMA16(1, 1); PRIO0();
        if (last) { VM0(); } else { VM4(); }
        BARX();
        DS_A(1, 0); DS_B(1, 0); if (h2) STG_A(0, 1, t2k);
        BARX(); PRIO1(); MFMA16(0, 0); PRIO0(); BARX();
        DS_B(1, 1); if (h2) STG_B(0, 1, t2k);
        BARX(); PRIO1(); MFMA16(0, 1); PRIO0(); BARX();
        DS_A(1, 1); if (h3) STG_A(1, 0, t3k);
        BARX(); PRIO1(); MFMA16(1, 0); PRIO0(); BARX();
        if (h3) STG_B(1, 0, t3k);
        BARX(); PRIO1(); MFMA16(1, 1); PRIO0();
        if (last) { VM0(); } else { VM4(); }
        BARX();
    }

#pragma unroll
    for (int fmg = 0; fmg < 8; ++fmg) {
#pragma unroll
        for (int fng = 0; fng < 4; ++fng) {
            const int col = n0 + wn * 64 + fng * 16 + lr;
#pragma unroll
            for (int r = 0; r < 4; ++r) {
                const int row = m0 + wm * 128 + fmg * 16 + g * 4 + r;
                const float v = acc[fmg][fng][r];
                if (EPI == 0) {
                    Cb[(size_t)row * Nc + col] = f2bf(v);
                } else {
                    Cf[(size_t)row * Nc + col] = v + bias[col] + bf2f(Qf[(size_t)row * 2304 + col]);
                }
            }
        }
    }
#undef STG_A
#undef STG_B
#undef DS_A
#undef DS_B
#undef MM
#undef MFMA8
#undef MFMA16
}

// ---------------- fused softmax-weighted global vector (single pass) ----------------
// Per block: (bh, sp). Reads 256 rows x 64 cols of qkv slice (col_off + h*64),
// computes d_n = SCALE * row_n . vec, emits partial {m, s, vec64} (unnormalized).
// partv: [B*H*NS2][64], partms: [B*H*NS2][2]
__global__ __launch_bounds__(256)
void fused_path(const unsigned short* __restrict__ qkv, int col_off,
                const float* __restrict__ vec, int per_bh,
                float* __restrict__ partv, float* __restrict__ partms)
{
    const int bid = blockIdx.x;
    const int bh = bid / NS2, sp = bid % NS2;
    const int b = bh / H_, h = bh % H_;
    const int t = threadIdx.x;
    const int lane8 = t & 7, grp = t >> 3;      // 32 groups, 8 lanes each

    const unsigned short* base = qkv + ((size_t)(b * N_ + sp * 256) * 2304)
                                 + col_off + h * 64 + lane8 * 8;
    const float* wv = vec + (per_bh ? bh * 64 : h * 64) + lane8 * 8;
    float w8[8];
#pragma unroll
    for (int j = 0; j < 8; j++) w8[j] = wv[j];

    float q[8][8];
    float d[8];
#pragma unroll
    for (int pass = 0; pass < 8; ++pass) {
        const int row = pass * 32 + grp;
        s8v q8 = *(const s8v*)(base + (size_t)row * 2304);
        float s = 0.f;
#pragma unroll
        for (int j = 0; j < 8; j++) {
            q[pass][j] = bf2f((unsigned short)q8[j]);
            s += q[pass][j] * w8[j];
        }
        s += __shfl_xor(s, 1); s += __shfl_xor(s, 2); s += __shfl_xor(s, 4);
        d[pass] = s * SCALE_;
    }
    float m = d[0];
#pragma unroll
    for (int pass = 1; pass < 8; ++pass) m = fmaxf(m, d[pass]);
    float ssum = 0.f;
    float a8[8] = {};
#pragma unroll
    for (int pass = 0; pass < 8; ++pass) {
        float e = __expf(d[pass] - m);
        ssum += e;
#pragma unroll
        for (int j = 0; j < 8; j++) a8[j] += e * q[pass][j];
    }

    // merge 32 groups
    __shared__ float Lm[32], Ls[32];
    __shared__ float La[32][64];
    if (lane8 == 0) { Lm[grp] = m; Ls[grp] = ssum; }
#pragma unroll
    for (int j = 0; j < 8; j++) La[grp][lane8 * 8 + j] = a8[j];
    __syncthreads();

    if (t < 64) {
        float mstar = Lm[0];
#pragma unroll
        for (int g2 = 1; g2 < 32; ++g2) mstar = fmaxf(mstar, Lm[g2]);
        float sstar = 0.f, v = 0.f;
#pragma unroll
        for (int g2 = 0; g2 < 32; ++g2) {
            float e = __expf(Lm[g2] - mstar);
            sstar += Ls[g2] * e;
            v += La[g2][t] * e;
        }
        partv[(size_t)bid * 64 + t] = v;
        if (t == 0) { partms[bid * 2] = mstar; partms[bid * 2 + 1] = sstar; }
    }
}

// combine NS2 partials per bh -> gout[bh][64]; optionally bvec = gout * wk[h]
__global__ void path_reduce(const float* __restrict__ partv, const float* __restrict__ partms,
                            float* __restrict__ gout,
                            const float* __restrict__ wk, float* __restrict__ bvec)
{
    const int bh = blockIdx.x;
    const int t = threadIdx.x;   // 64
    const int h = bh % H_;
    float mstar = partms[(bh * NS2) * 2];
#pragma unroll
    for (int p = 1; p < NS2; ++p) mstar = fmaxf(mstar, partms[(bh * NS2 + p) * 2]);
    float sstar = 0.f, v = 0.f;
#pragma unroll
    for (int p = 0; p < NS2; ++p) {
        float e = __expf(partms[(bh * NS2 + p) * 2] - mstar);
        sstar += partms[(bh * NS2 + p) * 2 + 1] * e;
        v += partv[(size_t)(bh * NS2 + p) * 64 + t] * e;
    }
    float g = v / sstar;
    gout[bh * 64 + t] = g;
    if (wk) bvec[bh * 64 + t] = g * wk[h * 64 + t];
}

// ---------------- small kernels ----------------

__global__ void cvt_kernel(const float* __restrict__ src, unsigned short* __restrict__ dst, int n4) {
    int i = blockIdx.x * 256 + threadIdx.x;
    if (i >= n4) return;
    float4 v = ((const float4*)src)[i];
    ushort4 o;
    o.x = f2bf(v.x); o.y = f2bf(v.y); o.z = f2bf(v.z); o.w = f2bf(v.w);
    ((ushort4*)dst)[i] = o;
}

// W2[b][j][c] = bf16(Wp[j][c] * gk[(b*H + c/64)*64 + c%64])
__global__ void fold_wp(const float* __restrict__ Wp, const float* __restrict__ gk,
                        unsigned short* __restrict__ W2) {
    int idx = blockIdx.x * 256 + threadIdx.x;
    int e4 = idx * 4;
    int b = (int)((unsigned)e4 / (unsigned)(DIM_ * DIM_));
    int rem = e4 - b * (DIM_ * DIM_);
    int c = rem % DIM_;
    float4 wv = *(const float4*)&Wp[rem];
    const float* gp = &gk[(b * H_ + (c >> 6)) * 64 + (c & 63)];
    ushort4 o;
    o.x = f2bf(wv.x * gp[0]); o.y = f2bf(wv.y * gp[1]);
    o.z = f2bf(wv.z * gp[2]); o.w = f2bf(wv.w * gp[3]);
    *(ushort4*)&W2[e4] = o;
}

extern "C" void kernel_launch(void* const* d_in, const int* in_sizes, int n_in,
                              void* d_out, int out_size, void* d_ws, size_t ws_size,
                              hipStream_t stream)
{
    const float* x    = (const float*)d_in[0];
    const float* Wqkv = (const float*)d_in[1];
    const float* Wp   = (const float*)d_in[2];
    const float* bp   = (const float*)d_in[3];
    const float* w_q  = (const float*)d_in[4];
    const float* w_k  = (const float*)d_in[5];
    float* out = (float*)d_out;

    constexpr size_t NXB   = (size_t)M_ * DIM_;
    constexpr size_t NWQKV = (size_t)3 * DIM_ * DIM_;
    constexpr size_t NQKV  = (size_t)M_ * 3 * DIM_;
    constexpr size_t NW2   = (size_t)B_ * DIM_ * DIM_;

    char* p = (char*)d_ws;
    unsigned short* xb    = (unsigned short*)p; p += NXB * 2;
    unsigned short* wqkvb = (unsigned short*)p; p += NWQKV * 2;
    unsigned short* qkvb  = (unsigned short*)p; p += NQKV * 2;
    unsigned short* w2b   = (unsigned short*)p; p += NW2 * 2;
    float* partv = (float*)p; p += (size_t)B_ * H_ * NS2 * 64 * 4;
    float* partms= (float*)p; p += (size_t)B_ * H_ * NS2 * 2 * 4;
    float* gq    = (float*)p; p += (size_t)B_ * H_ * 64 * 4;
    float* bvec  = (float*)p; p += (size_t)B_ * H_ * 64 * 4;
    float* gk    = (float*)p; p += (size_t)B_ * H_ * 64 * 4;

    // 1) convert x, Wqkv to bf16
    cvt_kernel<<<(int)(NXB / 4 + 255) / 256, 256, 0, stream>>>(x, xb, (int)(NXB / 4));
    cvt_kernel<<<(int)(NWQKV / 4 + 255) / 256, 256, 0, stream>>>(Wqkv, wqkvb, (int)(NWQKV / 4));

    // 2) qkv = x @ Wqkv^T  [M, 2304] bf16
    gemm8<0><<<128 * 9, 512, 0, stream>>>(xb, DIM_, wqkvb, qkvb, nullptr, nullptr, nullptr,
                                          3 * DIM_, 9);

    // 3) alpha path (q): single-pass partials + reduce (bvec = gq * w_k)
    fused_path<<<B_ * H_ * NS2, 256, 0, stream>>>(qkvb, 0, w_q, 0, partv, partms);
    path_reduce<<<B_ * H_, 64, 0, stream>>>(partv, partms, gq, w_k, bvec);

    // 4) beta path (k): vec = bvec (per-bh)
    fused_path<<<B_ * H_ * NS2, 256, 0, stream>>>(qkvb, DIM_, bvec, 1, partv, partms);
    path_reduce<<<B_ * H_, 64, 0, stream>>>(partv, partms, gk, nullptr, nullptr);

    // 5) fold gk into Wp: W2[b] = Wp * gk_b (bf16)
    fold_wp<<<(int)(NW2 / 4 / 256), 256, 0, stream>>>(Wp, gk, w2b);

    // 6) out = v @ W2_b^T + bp + q_flat
    gemm8<1><<<128 * 3, 512, 0, stream>>>(qkvb + 1536, 2304, w2b, nullptr, out, bp, qkvb,
                                          DIM_, 3);
}

// Round 4
// 245.373 us; speedup vs baseline: 1.6089x; 1.0274x over previous
//
#include <hip/hip_runtime.h>
#include <hip/hip_bf16.h>
#include <cstdint>
#include <cstddef>

#define B_ 8
#define N_ 4096
#define DIM_ 768
#define H_ 12
#define M_ (B_*N_)        // 32768
#define SCALE_ 0.125f
#define NS2 16            // row-splits per (b,h) for fused path
#define KDIM 768
#define NKT 12            // K tiles of 64
#define NITER 6           // NKT/2

typedef __attribute__((ext_vector_type(8))) short s8v;
typedef __attribute__((ext_vector_type(4))) float f4v;

__device__ inline float bf2f(unsigned short u) {
    unsigned v = ((unsigned)u) << 16;
    return __builtin_bit_cast(float, v);
}
__device__ inline unsigned short f2bf(float f) {
    unsigned u = __builtin_bit_cast(unsigned, f);
    return (unsigned short)((u + 0x7FFFu + ((u >> 16) & 1u)) >> 16);
}
__device__ inline void gload16(const void* g, void* l) {
    __builtin_amdgcn_global_load_lds(
        (const __attribute__((address_space(1))) void*)g,
        (__attribute__((address_space(3))) void*)l, 16, 0, 0);
}

#define BARX() __builtin_amdgcn_s_barrier()
#define PRIO1() __builtin_amdgcn_s_setprio(1)
#define PRIO0() __builtin_amdgcn_s_setprio(0)
#define VM4() asm volatile("s_waitcnt vmcnt(4)" ::: "memory")
#define VM0() asm volatile("s_waitcnt vmcnt(0)" ::: "memory")

// ---------------- 256x256 8-phase bf16 GEMM: C = A[M,768] @ B[Nc,768]^T ----------------
// EPI==0: store bf16 to Cb.
template<int EPI>
__global__ __launch_bounds__(512, 2)
void gemm8(const unsigned short* __restrict__ A, int ldaE,
           const unsigned short* __restrict__ Bmat,
           unsigned short* __restrict__ Cb, float* __restrict__ Cf,
           const float* __restrict__ bias, const unsigned short* __restrict__ Qf,
           int Nc, int ntn)
{
    __shared__ __align__(16) char smem[131072];   // 2 bufs x 4 regions x 16KB
    const int tid = threadIdx.x;
    const int l = tid & 63, w = tid >> 6;
    const int lr = l & 15, g = l >> 4;
    const int wm = w >> 2, wn = w & 3;

    const int nwg = gridDim.x, cpx = nwg >> 3;
    const int bid = blockIdx.x;
    const int lg = (bid & 7) * cpx + (bid >> 3);
    const int tm = lg / ntn, tn = lg % ntn;
    const int m0 = tm * 256, n0 = tn * 256;

    const long ldaB = (long)ldaE * 2;
    const long ldbB = (long)KDIM * 2;

    const unsigned short* Bp = Bmat;
    if (EPI == 1) Bp = Bmat + (size_t)(m0 >> 12) * (DIM_ * DIM_);

    const int srA = w * 8 + (l >> 3);
    const int kbs = (l & 7) * 16;
    const int kbx = kbs ^ ((srA & 7) << 4);
    long offA[2], offB[2];
    offA[0] = (long)(srA) * ldaB + kbx;
    offA[1] = (long)(128 + srA) * ldaB + kbx;
    offB[0] = (long)(((srA >> 5)) * 64 + (srA & 31)) * ldbB + kbx;
    offB[1] = (long)((2 + (srA >> 5)) * 64 + (srA & 31)) * ldbB + kbx;

    const char* Abase = (const char*)(A + (size_t)m0 * ldaE);
    const char* Bbase = (const char*)(Bp + (size_t)n0 * KDIM);

    const int aoff = (wm * 64 + lr) * 128;
    const int boff = (wn * 32 + lr) * 128;
    const int kx0 = (g * 16) ^ ((lr & 7) << 4);
    const int kx1 = (64 + g * 16) ^ ((lr & 7) << 4);

    f4v acc[8][4] = {};
    s8v af[4][2];
    s8v bfr[2][2][2];

#define STG_A(buf_, qm_, kt_) { \
    const char* s0_ = Abase + (long)(kt_) * 2 + (long)(qm_) * 64 * ldaB; \
    char* d0_ = smem + ((buf_) * 4 + (qm_)) * 16384 + w * 1024; \
    gload16(s0_ + offA[0], d0_); \
    gload16(s0_ + offA[1], d0_ + 8192); }

#define STG_B(buf_, qn_, kt_) { \
    const char* s0_ = Bbase + (long)(kt_) * 2 + (long)(qn_) * 32 * ldbB; \
    char* d0_ = smem + ((buf_) * 4 + 2 + (qn_)) * 16384 + w * 1024; \
    gload16(s0_ + offB[0], d0_); \
    gload16(s0_ + offB[1], d0_ + 8192); }

#define DS_A(buf_, qm_) { \
    const char* ba_ = smem + ((buf_) * 4 + (qm_)) * 16384 + aoff; \
    af[0][0] = *(const s8v*)(ba_ +    0 + kx0); af[0][1] = *(const s8v*)(ba_ +    0 + kx1); \
    af[1][0] = *(const s8v*)(ba_ + 2048 + kx0); af[1][1] = *(const s8v*)(ba_ + 2048 + kx1); \
    af[2][0] = *(const s8v*)(ba_ + 4096 + kx0); af[2][1] = *(const s8v*)(ba_ + 4096 + kx1); \
    af[3][0] = *(const s8v*)(ba_ + 6144 + kx0); af[3][1] = *(const s8v*)(ba_ + 6144 + kx1); }

#define DS_B(buf_, qn_) { \
    const char* bb_ = smem + ((buf_) * 4 + 2 + (qn_)) * 16384 + boff; \
    bfr[qn_][0][0] = *(const s8v*)(bb_ +    0 + kx0); bfr[qn_][0][1] = *(const s8v*)(bb_ +    0 + kx1); \
    bfr[qn_][1][0] = *(const s8v*)(bb_ + 2048 + kx0); bfr[qn_][1][1] = *(const s8v*)(bb_ + 2048 + kx1); }

#define MM(fmg_, fng_, qn_, kk_) \
    acc[fmg_][fng_] = __builtin_amdgcn_mfma_f32_16x16x32_bf16(af[(fmg_)&3][kk_], bfr[qn_][(fng_)&1][kk_], acc[fmg_][fng_], 0, 0, 0);

#define MFMA8(qm_, qn_, kk_) \
    MM((qm_)*4+0, (qn_)*2+0, qn_, kk_) MM((qm_)*4+0, (qn_)*2+1, qn_, kk_) \
    MM((qm_)*4+1, (qn_)*2+0, qn_, kk_) MM((qm_)*4+1, (qn_)*2+1, qn_, kk_) \
    MM((qm_)*4+2, (qn_)*2+0, qn_, kk_) MM((qm_)*4+2, (qn_)*2+1, qn_, kk_) \
    MM((qm_)*4+3, (qn_)*2+0, qn_, kk_) MM((qm_)*4+3, (qn_)*2+1, qn_, kk_)

#define MFMA16(qm_, qn_) { MFMA8(qm_, qn_, 0) MFMA8(qm_, qn_, 1) }

    STG_A(0, 0, 0); STG_B(0, 0, 0); STG_A(0, 1, 0); STG_B(0, 1, 0);
    STG_A(1, 0, 64); STG_B(1, 0, 64);
    VM4(); BARX();

    for (int i = 0; i < NITER; ++i) {
        const int t1k = (2 * i + 1) * 64, t2k = (2 * i + 2) * 64, t3k = (2 * i + 3) * 64;
        const bool h2 = (2 * i + 2) < NKT, h3 = (2 * i + 3) < NKT;
        const bool last = (i == NITER - 1);
        DS_A(0, 0); DS_B(0, 0); STG_B(1, 1, t1k);
        BARX(); PRIO1(); MFMA16(0, 0); PRIO0(); BARX();
        DS_B(0, 1); STG_A(1, 1, t1k);
        BARX(); PRIO1(); MFMA16(0, 1); PRIO0(); BARX();
        DS_A(0, 1); if (h2) STG_A(0, 0, t2k);
        BARX(); PRIO1(); MFMA16(1, 0); PRIO0(); BARX();
        if (h2) STG_B(0, 0, t2k);
        BARX(); PRIO1(); MFMA16(1, 1); PRIO0();
        if (last) { VM0(); } else { VM4(); }
        BARX();
        DS_A(1, 0); DS_B(1, 0); if (h2) STG_A(0, 1, t2k);
        BARX(); PRIO1(); MFMA16(0, 0); PRIO0(); BARX();
        DS_B(1, 1); if (h2) STG_B(0, 1, t2k);
        BARX(); PRIO1(); MFMA16(0, 1); PRIO0(); BARX();
        DS_A(1, 1); if (h3) STG_A(1, 0, t3k);
        BARX(); PRIO1(); MFMA16(1, 0); PRIO0(); BARX();
        if (h3) STG_B(1, 0, t3k);
        BARX(); PRIO1(); MFMA16(1, 1); PRIO0();
        if (last) { VM0(); } else { VM4(); }
        BARX();
    }

#pragma unroll
    for (int fmg = 0; fmg < 8; ++fmg) {
#pragma unroll
        for (int fng = 0; fng < 4; ++fng) {
            const int col = n0 + wn * 64 + fng * 16 + lr;
#pragma unroll
            for (int r = 0; r < 4; ++r) {
                const int row = m0 + wm * 128 + fmg * 16 + g * 4 + r;
                const float v = acc[fmg][fng][r];
                if (EPI == 0) {
                    Cb[(size_t)row * Nc + col] = f2bf(v);
                } else {
                    Cf[(size_t)row * Nc + col] = v + bias[col] + bf2f(Qf[(size_t)row * 2304 + col]);
                }
            }
        }
    }
#undef STG_A
#undef STG_B
#undef DS_A
#undef DS_B
}

// ---------------- 128x256 4-phase bf16 GEMM with f32 epilogue ----------------
// Cf[row, col] = sum_k A[row,k]*Bb[col,k] + bias[col] + bf2f(Qf[row*2304+col])
// Bb = Bmat + (row/4096)*DIM_*DIM_ (per-batch weight). A has row stride ldaE.
// Grid: (M/128) * ntn blocks; 512 threads.  LDS: 2 bufs x 3 regions x 16KB = 96KB.
__global__ __launch_bounds__(512, 2)
void gemm128_epi(const unsigned short* __restrict__ A, int ldaE,
                 const unsigned short* __restrict__ Bmat,
                 float* __restrict__ Cf,
                 const float* __restrict__ bias, const unsigned short* __restrict__ Qf,
                 int Nc, int ntn)
{
    __shared__ __align__(16) char smem[98304];
    const int tid = threadIdx.x;
    const int l = tid & 63, w = tid >> 6;
    const int lr = l & 15, g = l >> 4;
    const int wm = w >> 2, wn = w & 3;     // 2M x 4N waves; per-wave 64x64

    const int nwg = gridDim.x, cpx = nwg >> 3;
    const int bid = blockIdx.x;
    const int lg = (bid & 7) * cpx + (bid >> 3);
    const int tm = lg / ntn, tn = lg % ntn;
    const int m0 = tm * 128, n0 = tn * 256;

    const long ldaB = (long)ldaE * 2;
    const long ldbB = (long)KDIM * 2;

    const unsigned short* Bp = Bmat + (size_t)(m0 >> 12) * (DIM_ * DIM_);

    const int srA = w * 8 + (l >> 3);
    const int kbs = (l & 7) * 16;
    const int kbx = kbs ^ ((srA & 7) << 4);
    long offA[2], offB[2];
    offA[0] = (long)(srA) * ldaB + kbx;          // A region: rows 0-63 then 64-127
    offA[1] = (long)(64 + srA) * ldaB + kbx;
    offB[0] = (long)(((srA >> 5)) * 64 + (srA & 31)) * ldbB + kbx;
    offB[1] = (long)((2 + (srA >> 5)) * 64 + (srA & 31)) * ldbB + kbx;

    const char* Abase = (const char*)(A + (size_t)m0 * ldaE);
    const char* Bbase = (const char*)(Bp + (size_t)n0 * KDIM);

    const int aoff = (wm * 64 + lr) * 128;
    const int boff = (wn * 32 + lr) * 128;
    const int kx0 = (g * 16) ^ ((lr & 7) << 4);
    const int kx1 = (64 + g * 16) ^ ((lr & 7) << 4);

    f4v acc[4][4] = {};
    s8v af[4][2];
    s8v bfr[2][2][2];

    // region index: buf*3 + {0:A, 1:B0, 2:B1}
#define STG_A1(buf_, kt_) { \
    const char* s0_ = Abase + (long)(kt_) * 2; \
    char* d0_ = smem + ((buf_) * 3) * 16384 + w * 1024; \
    gload16(s0_ + offA[0], d0_); \
    gload16(s0_ + offA[1], d0_ + 8192); }

#define STG_B1(buf_, qn_, kt_) { \
    const char* s0_ = Bbase + (long)(kt_) * 2 + (long)(qn_) * 32 * ldbB; \
    char* d0_ = smem + ((buf_) * 3 + 1 + (qn_)) * 16384 + w * 1024; \
    gload16(s0_ + offB[0], d0_); \
    gload16(s0_ + offB[1], d0_ + 8192); }

#define DS_A1(buf_) { \
    const char* ba_ = smem + ((buf_) * 3) * 16384 + aoff; \
    af[0][0] = *(const s8v*)(ba_ +    0 + kx0); af[0][1] = *(const s8v*)(ba_ +    0 + kx1); \
    af[1][0] = *(const s8v*)(ba_ + 2048 + kx0); af[1][1] = *(const s8v*)(ba_ + 2048 + kx1); \
    af[2][0] = *(const s8v*)(ba_ + 4096 + kx0); af[2][1] = *(const s8v*)(ba_ + 4096 + kx1); \
    af[3][0] = *(const s8v*)(ba_ + 6144 + kx0); af[3][1] = *(const s8v*)(ba_ + 6144 + kx1); }

#define DS_B1(buf_, qn_) { \
    const char* bb_ = smem + ((buf_) * 3 + 1 + (qn_)) * 16384 + boff; \
    bfr[qn_][0][0] = *(const s8v*)(bb_ +    0 + kx0); bfr[qn_][0][1] = *(const s8v*)(bb_ +    0 + kx1); \
    bfr[qn_][1][0] = *(const s8v*)(bb_ + 2048 + kx0); bfr[qn_][1][1] = *(const s8v*)(bb_ + 2048 + kx1); }

#define MM1(fm_, fng_, qn_, kk_) \
    acc[fm_][fng_] = __builtin_amdgcn_mfma_f32_16x16x32_bf16(af[fm_][kk_], bfr[qn_][(fng_)&1][kk_], acc[fm_][fng_], 0, 0, 0);

#define MFMA16_1(qn_, kk_) \
    MM1(0, (qn_)*2+0, qn_, kk_) MM1(0, (qn_)*2+1, qn_, kk_) \
    MM1(1, (qn_)*2+0, qn_, kk_) MM1(1, (qn_)*2+1, qn_, kk_) \
    MM1(2, (qn_)*2+0, qn_, kk_) MM1(2, (qn_)*2+1, qn_, kk_) \
    MM1(3, (qn_)*2+0, qn_, kk_) MM1(3, (qn_)*2+1, qn_, kk_)

#define MFMA32_1(qn_) { MFMA16_1(qn_, 0) MFMA16_1(qn_, 1) }

    // prologue: T0 {A,B0,B1}, T1 {A,B0}  -> 10 loads; wait leaves T1.A,B0
    STG_A1(0, 0); STG_B1(0, 0, 0); STG_B1(0, 1, 0);
    STG_A1(1, 64); STG_B1(1, 0, 64);
    VM4(); BARX();

    for (int i = 0; i < NITER; ++i) {
        const int t1k = (2 * i + 1) * 64, t2k = (2 * i + 2) * 64, t3k = (2 * i + 3) * 64;
        const bool h2 = (2 * i + 2) < NKT, h3 = (2 * i + 3) < NKT;
        const bool last = (i == NITER - 1);
        // ph1: buf0, qn=0
        DS_A1(0); DS_B1(0, 0); STG_B1(1, 1, t1k);
        BARX(); PRIO1(); MFMA32_1(0); PRIO0(); BARX();
        // ph2: buf0, qn=1 ; stage T2.A + T2.B0 ; drain T1
        DS_B1(0, 1); if (h2) { STG_A1(0, t2k); STG_B1(0, 0, t2k); }
        BARX(); PRIO1(); MFMA32_1(1); PRIO0();
        if (last) { VM0(); } else { VM4(); }
        BARX();
        // ph3: buf1, qn=0
        DS_A1(1); DS_B1(1, 0); if (h2) STG_B1(0, 1, t2k);
        BARX(); PRIO1(); MFMA32_1(0); PRIO0(); BARX();
        // ph4: buf1, qn=1 ; stage T3.A + T3.B0 ; drain T2
        DS_B1(1, 1); if (h3) { STG_A1(1, t3k); STG_B1(1, 0, t3k); }
        BARX(); PRIO1(); MFMA32_1(1); PRIO0();
        if (last) { VM0(); } else { VM4(); }
        BARX();
    }

#pragma unroll
    for (int fm = 0; fm < 4; ++fm) {
#pragma unroll
        for (int fng = 0; fng < 4; ++fng) {
            const int col = n0 + wn * 64 + fng * 16 + lr;
#pragma unroll
            for (int r = 0; r < 4; ++r) {
                const int row = m0 + wm * 64 + fm * 16 + g * 4 + r;
                Cf[(size_t)row * Nc + col] = acc[fm][fng][r] + bias[col]
                                             + bf2f(Qf[(size_t)row * 2304 + col]);
            }
        }
    }
#undef STG_A1
#undef STG_B1
#undef DS_A1
#undef DS_B1
#undef MM1
#undef MFMA16_1
#undef MFMA32_1
}

// ---------------- fused softmax-weighted global vector (single pass) ----------------
__global__ __launch_bounds__(256)
void fused_path(const unsigned short* __restrict__ qkv, int col_off,
                const float* __restrict__ vec, int per_bh,
                float* __restrict__ partv, float* __restrict__ partms)
{
    const int bid = blockIdx.x;
    const int bh = bid / NS2, sp = bid % NS2;
    const int b = bh / H_, h = bh % H_;
    const int t = threadIdx.x;
    const int lane8 = t & 7, grp = t >> 3;

    const unsigned short* base = qkv + ((size_t)(b * N_ + sp * 256) * 2304)
                                 + col_off + h * 64 + lane8 * 8;
    const float* wv = vec + (per_bh ? bh * 64 : h * 64) + lane8 * 8;
    float w8[8];
#pragma unroll
    for (int j = 0; j < 8; j++) w8[j] = wv[j];

    float q[8][8];
    float d[8];
#pragma unroll
    for (int pass = 0; pass < 8; ++pass) {
        const int row = pass * 32 + grp;
        s8v q8 = *(const s8v*)(base + (size_t)row * 2304);
        float s = 0.f;
#pragma unroll
        for (int j = 0; j < 8; j++) {
            q[pass][j] = bf2f((unsigned short)q8[j]);
            s += q[pass][j] * w8[j];
        }
        s += __shfl_xor(s, 1); s += __shfl_xor(s, 2); s += __shfl_xor(s, 4);
        d[pass] = s * SCALE_;
    }
    float m = d[0];
#pragma unroll
    for (int pass = 1; pass < 8; ++pass) m = fmaxf(m, d[pass]);
    float ssum = 0.f;
    float a8[8] = {};
#pragma unroll
    for (int pass = 0; pass < 8; ++pass) {
        float e = __expf(d[pass] - m);
        ssum += e;
#pragma unroll
        for (int j = 0; j < 8; j++) a8[j] += e * q[pass][j];
    }

    __shared__ float Lm[32], Ls[32];
    __shared__ float La[32][64];
    if (lane8 == 0) { Lm[grp] = m; Ls[grp] = ssum; }
#pragma unroll
    for (int j = 0; j < 8; j++) La[grp][lane8 * 8 + j] = a8[j];
    __syncthreads();

    if (t < 64) {
        float mstar = Lm[0];
#pragma unroll
        for (int g2 = 1; g2 < 32; ++g2) mstar = fmaxf(mstar, Lm[g2]);
        float sstar = 0.f, v = 0.f;
#pragma unroll
        for (int g2 = 0; g2 < 32; ++g2) {
            float e = __expf(Lm[g2] - mstar);
            sstar += Ls[g2] * e;
            v += La[g2][t] * e;
        }
        partv[(size_t)bid * 64 + t] = v;
        if (t == 0) { partms[bid * 2] = mstar; partms[bid * 2 + 1] = sstar; }
    }
}

__global__ void path_reduce(const float* __restrict__ partv, const float* __restrict__ partms,
                            float* __restrict__ gout,
                            const float* __restrict__ wk, float* __restrict__ bvec)
{
    const int bh = blockIdx.x;
    const int t = threadIdx.x;
    const int h = bh % H_;
    float mstar = partms[(bh * NS2) * 2];
#pragma unroll
    for (int p = 1; p < NS2; ++p) mstar = fmaxf(mstar, partms[(bh * NS2 + p) * 2]);
    float sstar = 0.f, v = 0.f;
#pragma unroll
    for (int p = 0; p < NS2; ++p) {
        float e = __expf(partms[(bh * NS2 + p) * 2] - mstar);
        sstar += partms[(bh * NS2 + p) * 2 + 1] * e;
        v += partv[(size_t)(bh * NS2 + p) * 64 + t] * e;
    }
    float g = v / sstar;
    gout[bh * 64 + t] = g;
    if (wk) bvec[bh * 64 + t] = g * wk[h * 64 + t];
}

// ---------------- small kernels ----------------

__global__ void cvt_kernel(const float* __restrict__ src, unsigned short* __restrict__ dst, int n4) {
    int i = blockIdx.x * 256 + threadIdx.x;
    if (i >= n4) return;
    float4 v = ((const float4*)src)[i];
    ushort4 o;
    o.x = f2bf(v.x); o.y = f2bf(v.y); o.z = f2bf(v.z); o.w = f2bf(v.w);
    ((ushort4*)dst)[i] = o;
}

__global__ void fold_wp(const float* __restrict__ Wp, const float* __restrict__ gk,
                        unsigned short* __restrict__ W2) {
    int idx = blockIdx.x * 256 + threadIdx.x;
    int e4 = idx * 4;
    int b = (int)((unsigned)e4 / (unsigned)(DIM_ * DIM_));
    int rem = e4 - b * (DIM_ * DIM_);
    int c = rem % DIM_;
    float4 wv = *(const float4*)&Wp[rem];
    const float* gp = &gk[(b * H_ + (c >> 6)) * 64 + (c & 63)];
    ushort4 o;
    o.x = f2bf(wv.x * gp[0]); o.y = f2bf(wv.y * gp[1]);
    o.z = f2bf(wv.z * gp[2]); o.w = f2bf(wv.w * gp[3]);
    *(ushort4*)&W2[e4] = o;
}

extern "C" void kernel_launch(void* const* d_in, const int* in_sizes, int n_in,
                              void* d_out, int out_size, void* d_ws, size_t ws_size,
                              hipStream_t stream)
{
    const float* x    = (const float*)d_in[0];
    const float* Wqkv = (const float*)d_in[1];
    const float* Wp   = (const float*)d_in[2];
    const float* bp   = (const float*)d_in[3];
    const float* w_q  = (const float*)d_in[4];
    const float* w_k  = (const float*)d_in[5];
    float* out = (float*)d_out;

    constexpr size_t NXB   = (size_t)M_ * DIM_;
    constexpr size_t NWQKV = (size_t)3 * DIM_ * DIM_;
    constexpr size_t NQKV  = (size_t)M_ * 3 * DIM_;
    constexpr size_t NW2   = (size_t)B_ * DIM_ * DIM_;

    char* p = (char*)d_ws;
    unsigned short* xb    = (unsigned short*)p; p += NXB * 2;
    unsigned short* wqkvb = (unsigned short*)p; p += NWQKV * 2;
    unsigned short* qkvb  = (unsigned short*)p; p += NQKV * 2;
    unsigned short* w2b   = (unsigned short*)p; p += NW2 * 2;
    float* partv = (float*)p; p += (size_t)B_ * H_ * NS2 * 64 * 4;
    float* partms= (float*)p; p += (size_t)B_ * H_ * NS2 * 2 * 4;
    float* gq    = (float*)p; p += (size_t)B_ * H_ * 64 * 4;
    float* bvec  = (float*)p; p += (size_t)B_ * H_ * 64 * 4;
    float* gk    = (float*)p; p += (size_t)B_ * H_ * 64 * 4;

    // 1) convert x, Wqkv to bf16
    cvt_kernel<<<(int)(NXB / 4 + 255) / 256, 256, 0, stream>>>(x, xb, (int)(NXB / 4));
    cvt_kernel<<<(int)(NWQKV / 4 + 255) / 256, 256, 0, stream>>>(Wqkv, wqkvb, (int)(NWQKV / 4));

    // 2) qkv = x @ Wqkv^T  [M, 2304] bf16
    gemm8<0><<<128 * 9, 512, 0, stream>>>(xb, DIM_, wqkvb, qkvb, nullptr, nullptr, nullptr,
                                          3 * DIM_, 9);

    // 3) alpha path (q)
    fused_path<<<B_ * H_ * NS2, 256, 0, stream>>>(qkvb, 0, w_q, 0, partv, partms);
    path_reduce<<<B_ * H_, 64, 0, stream>>>(partv, partms, gq, w_k, bvec);

    // 4) beta path (k)
    fused_path<<<B_ * H_ * NS2, 256, 0, stream>>>(qkvb, DIM_, bvec, 1, partv, partms);
    path_reduce<<<B_ * H_, 64, 0, stream>>>(partv, partms, gk, nullptr, nullptr);

    // 5) fold gk into Wp: W2[b] = Wp * gk_b (bf16)
    fold_wp<<<(int)(NW2 / 4 / 256), 256, 0, stream>>>(Wp, gk, w2b);

    // 6) out = v @ W2_b^T + bp + q_flat   (256 M-tiles x 3 N-tiles = 768 blocks, 3.0 rounds)
    gemm128_epi<<<256 * 3, 512, 0, stream>>>(qkvb + 1536, 2304, w2b, out, bp, qkvb,
                                             DIM_, 3);
}